// Round 9
// baseline (165.573 us; speedup 1.0000x reference)
//
#include <hip/hip_runtime.h>
#include <cstdint>

#define NPRI 33600
#define NGT  256
#define NCLS 80
#define KTOP 13
#define INF_F 1.0e8f
#define EPS_F 1e-7f
#define L10 3.3219280948873623f
#define SCN_T 512
#define NW   (SCN_T / 64)          // 8 waves per block
#define CAPI 4096                  // per-GT positive-iou values
#define CAPC 1024                  // per-GT cost candidates
#define RFIX 5.5f                  // fixed collect radius (strides)
#define NBX  32                    // 32x32 spatial bins (32px at IMG=1024)
#define NB   (NBX * NBX)
#define PREP_BLKS ((NPRI + 255) / 256)
#define NEGINF __int_as_float(0xff800000)

typedef unsigned long long u64;

__device__ __forceinline__ int get_label(const void* p, int j, int is64) {
    if (is64) return (int)((const long long*)p)[j];
    return ((const int*)p)[j];
}

// bin of a coordinate: floor(c/32) clamped. Monotone floor+clamp => for any
// lo <= c <= hi, bin(c) in [bin(lo), bin(hi)] — coverage holds for ANY range.
// MUST be byte-identical in k_prep (hist) and k_scatter (placement).
__device__ __forceinline__ int bin1(float c) {
    int b = (int)floorf(c * 0.03125f);
    return b < 0 ? 0 : (b > NBX - 1 ? NBX - 1 : b);
}

// ---------- wave helpers (reduce + broadcast) ----------
__device__ __forceinline__ float wave_max_bc_f32(float v) {
    #pragma unroll
    for (int off = 32; off > 0; off >>= 1) v = fmaxf(v, __shfl_down(v, off, 64));
    return __int_as_float(__builtin_amdgcn_readfirstlane(__float_as_int(v)));
}
__device__ __forceinline__ u64 wave_min_bc_u64(u64 v) {
    #pragma unroll
    for (int off = 32; off > 0; off >>= 1) { u64 o = __shfl_down(v, off, 64); v = (o < v) ? o : v; }
    unsigned lo = (unsigned)__builtin_amdgcn_readfirstlane((int)(v & 0xffffffffull));
    unsigned hi = (unsigned)__builtin_amdgcn_readfirstlane((int)(v >> 32));
    return (((u64)hi) << 32) | lo;
}
// f32 multiset per-wave top-13: ballot single-lane elimination preserves duplicates
template<int NSL>
__device__ __forceinline__ void wave_merge_max13_f32(float (&l)[NSL], float* dst, int lane) {
    int p = 0;
    for (int r = 0; r < KTOP; ++r) {
        float cur = NEGINF;
        #pragma unroll
        for (int s = 0; s < NSL; ++s) if (s == p) cur = l[NSL - 1 - s];
        float bm = wave_max_bc_f32(cur);
        u64 m = __ballot(cur == bm && bm != NEGINF);
        int first = __ffsll(m) - 1;
        if (lane == first) p++;
        if (lane == 0) dst[r] = bm;
    }
}
// u64 per-wave top-13 min (keys idx-distinct -> single match per round)
template<int NSL>
__device__ __forceinline__ void wave_merge_minN(u64 (&l)[NSL], u64* dst, int lane) {
    int p = 0;
    for (int r = 0; r < KTOP; ++r) {
        u64 cur = ~0ull;
        #pragma unroll
        for (int s = 0; s < NSL; ++s) if (s == p) cur = l[s];
        u64 bm = wave_min_bc_u64(cur);
        if (cur == bm && bm != ~0ull) p++;
        if (lane == 0) dst[r] = bm;
    }
}

// ---------- exact formulas (verbatim: bit-identical selection) ----------
__device__ __forceinline__ float iou_exact(float4 pb, float areap, float gx1, float gy1,
                                           float gx2, float gy2, float areag) {
    float iw = fmaxf(fminf(pb.z, gx2) - fmaxf(pb.x, gx1), 0.0f);
    float ih = fmaxf(fminf(pb.w, gy2) - fmaxf(pb.y, gy1), 0.0f);
    float inter = iw * ih;
    return inter / fmaxf(areap + areag - inter, 1e-6f);
}
__device__ __forceinline__ float cost_exact(float4 p2, float gcx, float gcy,
                                            float l, float iou) {
    float dx = p2.x - gcx, dy = p2.y - gcy;
    float dist = sqrtf(dx * dx + dy * dy) / p2.z;
    float soft = exp2f((dist - 3.0f) * L10);
    float sig = 1.0f / (1.0f + expf(-l));
    float dd = iou - sig;
    float bce = fmaxf(l, 0.0f) - l * iou + log1pf(expf(-fabsf(l)));
    float iouc = -logf(iou + EPS_F) * 3.0f;
    return bce * (dd * dd) + iouc + soft;
}

// ---------- prep: int64 detect + init + valid mask + packed array + bin hists ----------
// p2 = (px, py, stride, w) where w = valid ? (stride*RFIX)^2*(1+1e-5) : -1
__global__ __launch_bounds__(256) void k_prep(
        const float* __restrict__ priors, const float* __restrict__ gt,
        const void* labels, const float* __restrict__ pboxes,
        float4* __restrict__ pbp,
        int* count, int* firstgt, int* flag,
        int* histI, int* histC, int* maxbuf) {
    __shared__ float4 gbox[NGT];
    __shared__ int    gpad[NGT];
    __shared__ int    bad;
    const int tid = threadIdx.x;
    const int b = blockIdx.x;
    if (b == 0 && tid == 0) bad = 0;
    {
        float4 bx = ((const float4*)gt)[tid];
        gbox[tid] = bx;
        gpad[tid] = ((bx.x + bx.y + bx.z + bx.w) > 0.0f) ? 1 : 0;
    }
    __syncthreads();
    if (b == 0 && tid < 128) {
        long long v = ((const long long*)labels)[tid];   // first 1024B: in-bounds either layout
        if (v < 0 || v >= NCLS) atomicOr(&bad, 1);
    }
    int g = b * 256 + tid;
    if (g < NPRI) {
        count[g] = 0; firstgt[g] = NGT;
        float4 pr = ((const float4*)priors)[g];
        float px = pr.x, py = pr.y;
        int v = 0;
        for (int j = 0; j < NGT; ++j) {
            float4 bx = gbox[j];
            float m = fminf(fminf(px - bx.x, py - bx.y), fminf(bx.z - px, bx.w - py));
            if (m > 0.0f && gpad[j]) { v = 1; break; }
        }
        float rad = pr.z * RFIX;
        float w = v ? rad * rad * (1.0f + 1e-5f) : -1.0f;
        float4 pb = ((const float4*)pboxes)[g];
        pbp[2 * g]     = pb;
        pbp[2 * g + 1] = make_float4(px, py, pr.z, w);
        // --- bin histograms + data-derived safety margins ---
        float pcx = (pb.x + pb.z) * 0.5f, pcy = (pb.y + pb.w) * 0.5f;
        atomicAdd(&histI[bin1(pcy) * NBX + bin1(pcx)], 1);
        atomicAdd(&histC[bin1(py) * NBX + bin1(px)], 1);
        float hw = fmaxf((pb.z - pb.x) * 0.5f, 0.0f);
        float hh = fmaxf((pb.w - pb.y) * 0.5f, 0.0f);
        atomicMax(&maxbuf[0], __float_as_int(fmaxf(hw, hh)));  // positive-float int order
        atomicMax(&maxbuf[1], __float_as_int(w));              // w<0 bits negative: ignored
    }
    if (b == 0) {
        __syncthreads();
        if (tid == 0) *flag = bad ? 0 : 1;   // 1 => int64 layout
    }
}

// ---------- exclusive prefix over both 1024-bin hists (one block) ----------
__global__ __launch_bounds__(NB) void k_bins(
        const int* __restrict__ histI, const int* __restrict__ histC,
        int* startI, int* startC, int* curI, int* curC) {
    __shared__ int sc[NB];
    const int t = threadIdx.x;
    int h = histI[t];
    sc[t] = h;
    __syncthreads();
    for (int off = 1; off < NB; off <<= 1) {
        int u = (t >= off) ? sc[t - off] : 0;
        __syncthreads();
        sc[t] += u;
        __syncthreads();
    }
    int excl = sc[t] - h;
    startI[t] = excl; curI[t] = excl;
    if (t == NB - 1) startI[NB] = sc[t];
    __syncthreads();
    h = histC[t];
    sc[t] = h;
    __syncthreads();
    for (int off = 1; off < NB; off <<= 1) {
        int u = (t >= off) ? sc[t - off] : 0;
        __syncthreads();
        sc[t] += u;
        __syncthreads();
    }
    excl = sc[t] - h;
    startC[t] = excl; curC[t] = excl;
    if (t == NB - 1) startC[NB] = sc[t];
}

// ---------- scatter into bin-sorted arrays (order within bin irrelevant) ----------
__global__ __launch_bounds__(256) void k_scatter(
        const float4* __restrict__ pbp,
        int* curI, int* curC,
        float4* __restrict__ A_pb, float4* __restrict__ A_pc) {
    const int i = blockIdx.x * 256 + threadIdx.x;
    if (i >= NPRI) return;
    float4 pb = pbp[2 * i];
    float4 p2 = pbp[2 * i + 1];
    float pcx = (pb.x + pb.z) * 0.5f, pcy = (pb.y + pb.w) * 0.5f;   // identical to k_prep
    int r = atomicAdd(&curI[bin1(pcy) * NBX + bin1(pcx)], 1);
    A_pb[r] = pb;
    int r2 = atomicAdd(&curC[bin1(p2.y) * NBX + bin1(p2.x)], 1);
    A_pc[r2] = make_float4(p2.x, p2.y, p2.w, __int_as_float(i));   // (px,py,w,idx bits)
}

// ---------- one 512-thr block per GT: BINNED collects + exact merges ----------
// Tested sets are provable supersets (margins M=2*hmax+1, rmax=sqrt(wmax)+1 from
// data maxima; floor+clamp monotone => range inclusion). Membership predicates
// unchanged => collected sets bit-identical to the full scan. Fallbacks (fI,
// mode-1, mode-2) remain exact full-range scans.
__global__ __launch_bounds__(SCN_T) void k_scan(
        const float* __restrict__ scores,
        const float4* __restrict__ pbp,
        const float4* __restrict__ A_pb, const float4* __restrict__ A_pc,
        const int* __restrict__ startI, const int* __restrict__ startC,
        const int* __restrict__ maxbuf,
        const float* __restrict__ gt, const void* labels, const int* flag,
        int* count, int* firstgt) {
    const int tid = threadIdx.x, lane = tid & 63, wid = tid >> 6;
    const int j = blockIdx.x;
    const int is64 = *flag;

    const float4 gb = ((const float4*)gt)[j];
    const float gx1 = gb.x, gy1 = gb.y, gx2 = gb.z, gy2 = gb.w;
    const float areag = (gx2 - gx1) * (gy2 - gy1);
    const float gcx = (gx1 + gx2) * 0.5f, gcy = (gy1 + gy2) * 0.5f;
    const int lab = get_label(labels, j, is64);
    const float hmax = __int_as_float(maxbuf[0]);
    const float wmax = __int_as_float(maxbuf[1]);
    const float M = 2.0f * hmax + 1.0f;                    // iou coverage margin
    const float rmax = sqrtf(fmaxf(wmax, 0.0f)) + 1.0f;    // ball coverage margin

    __shared__ int s_ni, s_nc, s_mode;
    __shared__ float s_dmax;
    __shared__ float liou[CAPI];
    __shared__ int lcost[CAPC];
    __shared__ float wiof[(NW - 1) * KTOP];   // 7 partial iou lists (waves 1..7)
    __shared__ u64 wco[NW * KTOP];            // mode-2 fallback only
    __shared__ u64 csel[KTOP];
    __shared__ float s_iou13[KTOP];
    if (tid == 0) { s_ni = 0; s_nc = 0; }
    __syncthreads();

    // ---- binned iou collect: bins covering pred-centers in [g-M, g+M] ----
    {
        int lox = bin1(gx1 - M), hix = bin1(gx2 + M);
        int loy = bin1(gy1 - M), hiy = bin1(gy2 + M);
        for (int by = loy; by <= hiy; ++by) {
            int s0 = startI[by * NBX + lox];
            int e0 = startI[by * NBX + hix + 1];
            for (int r = s0 + tid; r < e0; r += SCN_T) {
                float4 pb = A_pb[r];
                float areap = (pb.z - pb.x) * (pb.w - pb.y);
                float iou = iou_exact(pb, areap, gx1, gy1, gx2, gy2, areag);
                if (iou > 0.0f) {
                    int p = atomicAdd(&s_ni, 1);
                    if (p < CAPI) liou[p] = iou;
                }
            }
        }
    }
    // ---- binned cost collect: bins covering prior points in gc +- rmax ----
    {
        int lox = bin1(gcx - rmax), hix = bin1(gcx + rmax);
        int loy = bin1(gcy - rmax), hiy = bin1(gcy + rmax);
        for (int by = loy; by <= hiy; ++by) {
            int s0 = startC[by * NBX + lox];
            int e0 = startC[by * NBX + hix + 1];
            for (int r = s0 + tid; r < e0; r += SCN_T) {
                float4 pc = A_pc[r];                 // (px,py,w,idx)
                float dx = pc.x - gcx, dy = pc.y - gcy;
                if (dx * dx + dy * dy <= pc.z) {     // w=-1 invalid never passes
                    int p = atomicAdd(&s_nc, 1);
                    if (p < CAPC) lcost[p] = __float_as_int(pc.w);
                }
            }
        }
    }
    __syncthreads();
    const int ni = s_ni, nc = s_nc;
    const int ncc = (nc < CAPC) ? nc : CAPC;
    const bool fI = (ni > CAPI);

    // ---- phase 1: wave 0 = cost merge; waves 1..7 = iou partial merges ----
    if (wid == 0) {
        u64 lf[KTOP];
        #pragma unroll
        for (int s = 0; s < KTOP; ++s) lf[s] = ~0ull;
        for (int k = lane; k < ncc; k += 64) {   // <=16 per lane; 13-deep list complete
            int i = lcost[k];
            float4 pb = pbp[2 * i];
            float4 p2 = pbp[2 * i + 1];
            float areap = (pb.z - pb.x) * (pb.w - pb.y);
            float iou = iou_exact(pb, areap, gx1, gy1, gx2, gy2, areag);
            float ec = cost_exact(p2, gcx, gcy, scores[(size_t)i * NCLS + lab], iou);
            u64 ck = (((u64)__float_as_uint(ec)) << 32) | (unsigned)i;
            if (ck < lf[KTOP - 1]) {
                lf[KTOP - 1] = ck;
                #pragma unroll
                for (int s = KTOP - 1; s > 0; --s)
                    if (lf[s] < lf[s - 1]) { u64 t = lf[s]; lf[s] = lf[s - 1]; lf[s - 1] = t; }
            }
        }
        wave_merge_minN<KTOP>(lf, csel, lane);
        if (lane == 0) {
            u64 tk = csel[KTOP - 1];
            int mode; float dmax = 0.0f;
            if (tk == ~0ull) mode = 2;               // <13 candidates in RFIX ball
            else {
                float tau = __uint_as_float((unsigned)(tk >> 32));
                if (!(tau < 9.0e7f)) mode = 2;       // INF-ambiguity zone
                else {
                    dmax = 3.0f + __log2f(tau + 1e-5f) * (1.0f / L10) + 4e-3f;
                    mode = (dmax > RFIX || nc > CAPC) ? 1 : 0;
                }
            }
            s_mode = mode; s_dmax = dmax;
        }
    } else if (!fI) {
        float lf[KTOP];
        #pragma unroll
        for (int s = 0; s < KTOP; ++s) lf[s] = NEGINF;
        int nn = (ni < CAPI) ? ni : CAPI;
        for (int k = (wid - 1) * 64 + lane; k < nn; k += 64 * (NW - 1)) {
            float v = liou[k];
            if (v > lf[0]) {
                lf[0] = v;
                #pragma unroll
                for (int s = 0; s < KTOP - 1; ++s)
                    if (lf[s] > lf[s + 1]) { float t = lf[s]; lf[s] = lf[s + 1]; lf[s + 1] = t; }
            }
        }
        wave_merge_max13_f32<KTOP>(lf, &wiof[(wid - 1) * KTOP], lane);
    }
    __syncthreads();

    if (fI) {   // rare: iou list overflowed -> exact full rescan by waves 1..7
        if (wid > 0) {
            float lf[KTOP];
            #pragma unroll
            for (int s = 0; s < KTOP; ++s) lf[s] = NEGINF;
            for (int i = (wid - 1) * 64 + lane; i < NPRI; i += 64 * (NW - 1)) {
                float4 pb = pbp[2 * i];
                float areap = (pb.z - pb.x) * (pb.w - pb.y);
                float iou = iou_exact(pb, areap, gx1, gy1, gx2, gy2, areag);
                if (iou > 0.0f && iou > lf[0]) {
                    lf[0] = iou;
                    #pragma unroll
                    for (int s = 0; s < KTOP - 1; ++s)
                        if (lf[s] > lf[s + 1]) { float t = lf[s]; lf[s] = lf[s + 1]; lf[s + 1] = t; }
                }
            }
            wave_merge_max13_f32<KTOP>(lf, &wiof[(wid - 1) * KTOP], lane);
        }
        __syncthreads();
    }

    // ---- cross-merge the 7 iou lists -> s_iou13 (descending, multiset) ----
    if (wid == 0) {
        int p = 0;
        for (int r = 0; r < KTOP; ++r) {
            float cur = (lane < NW - 1 && p < KTOP) ? wiof[lane * KTOP + p] : NEGINF;
            float bm = wave_max_bc_f32(cur);
            u64 m = __ballot(cur == bm && bm != NEGINF);
            int first = __ffsll(m) - 1;
            if (lane == first) p++;
            if (lane == 0) s_iou13[r] = bm;
        }
    }

    int mode = s_mode;
    if (mode == 1) {   // re-collect at the sound radius Dmax' (rare, exact full scan)
        const float dmax = s_dmax;
        if (tid == 0) s_nc = 0;
        __syncthreads();
        for (int i = tid; i < NPRI; i += SCN_T) {
            float4 p2 = pbp[2 * i + 1];
            if (p2.w > 0.0f) {
                float dx = p2.x - gcx, dy = p2.y - gcy;
                float rad = p2.z * dmax;
                if (dx * dx + dy * dy <= rad * rad * (1.0f + 1e-5f)) {
                    int p = atomicAdd(&s_nc, 1);
                    if (p < CAPC) lcost[p] = i;
                }
            }
        }
        __syncthreads();
        int nc2 = s_nc;
        if (nc2 <= CAPC) {
            if (wid == 0) {
                u64 lf[KTOP];
                #pragma unroll
                for (int s = 0; s < KTOP; ++s) lf[s] = ~0ull;
                for (int k = lane; k < nc2; k += 64) {
                    int i = lcost[k];
                    float4 pb = pbp[2 * i];
                    float4 p2 = pbp[2 * i + 1];
                    float areap = (pb.z - pb.x) * (pb.w - pb.y);
                    float iou = iou_exact(pb, areap, gx1, gy1, gx2, gy2, areag);
                    float ec = cost_exact(p2, gcx, gcy, scores[(size_t)i * NCLS + lab], iou);
                    u64 ck = (((u64)__float_as_uint(ec)) << 32) | (unsigned)i;
                    if (ck < lf[KTOP - 1]) {
                        lf[KTOP - 1] = ck;
                        #pragma unroll
                        for (int s = KTOP - 1; s > 0; --s)
                            if (lf[s] < lf[s - 1]) { u64 t = lf[s]; lf[s] = lf[s - 1]; lf[s - 1] = t; }
                    }
                }
                wave_merge_minN<KTOP>(lf, csel, lane);
            }
        } else {
            mode = 2;   // uniform (s_nc shared)
        }
        __syncthreads();
    }
    if (mode == 2) {   // exact full scan (correctness net)
        u64 lf[KTOP];
        #pragma unroll
        for (int s = 0; s < KTOP; ++s) lf[s] = ~0ull;
        for (int i = tid; i < NPRI; i += SCN_T) {
            float4 pb = pbp[2 * i];
            float4 p2 = pbp[2 * i + 1];
            float areap = (pb.z - pb.x) * (pb.w - pb.y);
            float iou = iou_exact(pb, areap, gx1, gy1, gx2, gy2, areag);
            float ec = INF_F;
            if (p2.w > 0.0f) ec = cost_exact(p2, gcx, gcy, scores[(size_t)i * NCLS + lab], iou);
            u64 k2 = (((u64)__float_as_uint(ec)) << 32) | (unsigned)i;
            if (k2 < lf[KTOP - 1]) {
                lf[KTOP - 1] = k2;
                #pragma unroll
                for (int s = KTOP - 1; s > 0; --s)
                    if (lf[s] < lf[s - 1]) { u64 t = lf[s]; lf[s] = lf[s - 1]; lf[s - 1] = t; }
            }
        }
        wave_merge_minN<KTOP>(lf, &wco[wid * KTOP], lane);
        __syncthreads();
        if (wid == 0) {
            int p = 0;
            for (int r = 0; r < KTOP; ++r) {
                u64 cur = (lane < NW && p < KTOP) ? wco[lane * KTOP + p] : ~0ull;
                u64 bm = wave_min_bc_u64(cur);
                if (cur == bm && bm != ~0ull) p++;
                if (lane == 0) csel[r] = bm;
            }
        }
        __syncthreads();
    }

    // ---- finalize: ks from descending iou sum; scatter selections ----
    __syncthreads();
    if (wid == 0) {
        float tsum = 0.0f;
        #pragma unroll
        for (int r = 0; r < KTOP; ++r) {
            float v = s_iou13[r];
            tsum += (v == NEGINF) ? 0.0f : v;   // descending-order sum (missing = 0, as ref)
        }
        int ks = (int)tsum;
        if (ks < 1) ks = 1;
        if (lane < KTOP && lane < ks) {
            u64 mine = csel[lane];
            if (mine != ~0ull) {
                int idx = (int)(unsigned)(mine & 0xFFFFFFFFull);
                atomicAdd(&count[idx], 1);
                atomicMin(&firstgt[idx], j);
            }
        }
    }
}

// ---------- per-prior finalize; multi-matched priors resolved in-block ----------
__global__ __launch_bounds__(256) void k_assign(
        const float* __restrict__ scores,
        const float4* __restrict__ pbp, const float* __restrict__ gt,
        const void* labels, const int* flag,
        const int* __restrict__ count, const int* __restrict__ firstgt,
        float* __restrict__ out) {
    __shared__ float4 gbox[NGT];
    __shared__ int glab[NGT];
    __shared__ float gcxs[NGT], gcys[NGT], gareas[NGT];
    __shared__ int s_nm;
    __shared__ int s_mlist[256];
    __shared__ u64 red4[4];
    const int tid = threadIdx.x;
    const int is64 = *flag;
    {
        float4 b = ((const float4*)gt)[tid];
        gbox[tid] = b;
        glab[tid] = get_label(labels, tid, is64);
        gcxs[tid] = (b.x + b.z) * 0.5f;
        gcys[tid] = (b.y + b.w) * 0.5f;
        gareas[tid] = (b.z - b.x) * (b.w - b.y);
    }
    if (tid == 0) s_nm = 0;
    __syncthreads();
    const int i = blockIdx.x * 256 + tid;
    const bool act = (i < NPRI);
    if (act) {
        float4 p2 = pbp[2 * i + 1];
        int v = (p2.w > 0.0f) ? 1 : 0;
        int c = count[i];
        float o0 = 0.0f, o1 = -INF_F, o2 = -1.0f;
        if (v && c == 1) {
            int j = firstgt[i];
            float4 pb = pbp[2 * i];
            float areap = (pb.z - pb.x) * (pb.w - pb.y);
            float4 g = gbox[j];
            float iw = fmaxf(fminf(pb.z, g.z) - fmaxf(pb.x, g.x), 0.0f);
            float ih = fmaxf(fminf(pb.w, g.w) - fmaxf(pb.y, g.y), 0.0f);
            float inter = iw * ih;
            float iou = inter / fmaxf(areap + gareas[j] - inter, 1e-6f);
            o0 = (float)(j + 1); o1 = iou; o2 = (float)glab[j];
        } else if (v && c > 1) {
            int p = atomicAdd(&s_nm, 1);
            s_mlist[p] = i;
        }
        out[i] = o0;
        out[NPRI + i] = o1;
        out[2 * NPRI + i] = o2;
    }
    __syncthreads();
    // ---- in-block multi resolution: one GT per thread, block argmin per prior ----
    const int nm = s_nm;
    const int j = tid;
    for (int m = 0; m < nm; ++m) {
        const int ii = s_mlist[m];
        float4 pb = pbp[2 * ii];
        float4 p2 = pbp[2 * ii + 1];
        float areap = (pb.z - pb.x) * (pb.w - pb.y);

        float4 g = gbox[j];
        float iw = fmaxf(fminf(pb.z, g.z) - fmaxf(pb.x, g.x), 0.0f);
        float ih = fmaxf(fminf(pb.w, g.w) - fmaxf(pb.y, g.y), 0.0f);
        float inter = iw * ih;
        float iou = inter / fmaxf(areap + gareas[j] - inter, 1e-6f);
        float dx = p2.x - gcxs[j], dy = p2.y - gcys[j];
        float dist = sqrtf(dx * dx + dy * dy) / p2.z;
        float soft = exp2f((dist - 3.0f) * L10);
        float l = scores[(size_t)ii * NCLS + glab[j]];
        float sig = 1.0f / (1.0f + expf(-l));
        float dd = iou - sig;
        float bce = fmaxf(l, 0.0f) - l * iou + log1pf(expf(-fabsf(l)));
        float cost = bce * (dd * dd) + (-logf(iou + EPS_F) * 3.0f) + soft;

        u64 key = (((u64)__float_as_uint(cost)) << 32) | (unsigned)j;
        u64 v = key;
        #pragma unroll
        for (int off = 32; off > 0; off >>= 1) {
            u64 o = __shfl_down(v, off, 64);
            v = (o < v) ? o : v;
        }
        if ((tid & 63) == 0) red4[tid >> 6] = v;
        __syncthreads();
        u64 best = red4[0];
        #pragma unroll
        for (int q = 1; q < 4; ++q) best = (red4[q] < best) ? red4[q] : best;
        if (key == best) {
            out[ii] = (float)(j + 1);
            out[NPRI + ii] = iou;
            out[2 * NPRI + ii] = (float)glab[j];
        }
        __syncthreads();
    }
}

extern "C" void kernel_launch(void* const* d_in, const int* in_sizes, int n_in,
                              void* d_out, int out_size, void* d_ws, size_t ws_size,
                              hipStream_t stream) {
    const float* scores = (const float*)d_in[0];
    const float* priors = (const float*)d_in[1];
    const float* pboxes = (const float*)d_in[2];
    const float* gt     = (const float*)d_in[3];
    const void*  labels = d_in[4];
    float* out = (float*)d_out;

    char* ws = (char*)d_ws;
    size_t off = 0;
    auto alloc = [&](size_t bytes) { size_t o = off; off = (off + bytes + 255) & ~(size_t)255; return o; };
    int*    flag    = (int*)(ws + alloc(4));
    int*    count   = (int*)(ws + alloc((size_t)NPRI * 4));
    int*    firstgt = (int*)(ws + alloc((size_t)NPRI * 4));
    int*    histI   = (int*)(ws + alloc((size_t)(2 * NB + 2) * 4));   // histI|histC|maxbuf contiguous
    int*    histC   = histI + NB;
    int*    maxbuf  = histI + 2 * NB;
    int*    startI  = (int*)(ws + alloc((size_t)(NB + 1) * 4));
    int*    startC  = (int*)(ws + alloc((size_t)(NB + 1) * 4));
    int*    curI    = (int*)(ws + alloc((size_t)NB * 4));
    int*    curC    = (int*)(ws + alloc((size_t)NB * 4));
    float4* pbp     = (float4*)(ws + alloc((size_t)NPRI * 32));
    float4* A_pb    = (float4*)(ws + alloc((size_t)NPRI * 16));
    float4* A_pc    = (float4*)(ws + alloc((size_t)NPRI * 16));
    (void)ws_size;

    hipMemsetAsync(histI, 0, (size_t)(2 * NB + 2) * 4, stream);   // hists + max slots
    hipLaunchKernelGGL(k_prep, dim3(PREP_BLKS), dim3(256), 0, stream,
                       priors, gt, labels, pboxes, pbp, count, firstgt, flag,
                       histI, histC, maxbuf);
    hipLaunchKernelGGL(k_bins, dim3(1), dim3(NB), 0, stream,
                       histI, histC, startI, startC, curI, curC);
    hipLaunchKernelGGL(k_scatter, dim3(PREP_BLKS), dim3(256), 0, stream,
                       pbp, curI, curC, A_pb, A_pc);
    hipLaunchKernelGGL(k_scan, dim3(NGT), dim3(SCN_T), 0, stream,
                       scores, pbp, A_pb, A_pc, startI, startC, maxbuf,
                       gt, labels, flag, count, firstgt);
    hipLaunchKernelGGL(k_assign, dim3((NPRI + 255) / 256), dim3(256), 0, stream,
                       scores, pbp, gt, labels, flag, count, firstgt, out);
}

// Round 10
// 156.998 us; speedup vs baseline: 1.0546x; 1.0546x over previous
//
#include <hip/hip_runtime.h>
#include <cstdint>

#define NPRI 33600
#define NGT  256
#define NCLS 80
#define KTOP 13
#define INF_F 1.0e8f
#define EPS_F 1e-7f
#define L10 3.3219280948873623f
#define SCN_T 512
#define NW   (SCN_T / 64)          // 8 waves per block
#define CAPI 4096                  // per-GT positive-iou values
#define CAPC 1024                  // per-GT cost candidates
#define RFIX 5.5f                  // fixed collect radius (strides)
#define NBX  32                    // 32x32 spatial bins (32px at IMG=1024)
#define NB   (NBX * NBX)
#define PREP_BLKS ((NPRI + 255) / 256)
#define NEGINF __int_as_float(0xff800000)

typedef unsigned long long u64;

__device__ __forceinline__ int get_label(const void* p, int j, int is64) {
    if (is64) return (int)((const long long*)p)[j];
    return ((const int*)p)[j];
}

// bin of a coordinate: floor(c/32) clamped. Monotone floor+clamp => for any
// lo <= c <= hi, bin(c) in [bin(lo), bin(hi)] — coverage holds for ANY range.
// MUST be byte-identical in k_prep (hist) and k_scatter (placement).
__device__ __forceinline__ int bin1(float c) {
    int b = (int)floorf(c * 0.03125f);
    return b < 0 ? 0 : (b > NBX - 1 ? NBX - 1 : b);
}

// ---------- wave helpers (reduce + broadcast) ----------
__device__ __forceinline__ float wave_max_bc_f32(float v) {
    #pragma unroll
    for (int off = 32; off > 0; off >>= 1) v = fmaxf(v, __shfl_down(v, off, 64));
    return __int_as_float(__builtin_amdgcn_readfirstlane(__float_as_int(v)));
}
__device__ __forceinline__ u64 wave_min_bc_u64(u64 v) {
    #pragma unroll
    for (int off = 32; off > 0; off >>= 1) { u64 o = __shfl_down(v, off, 64); v = (o < v) ? o : v; }
    unsigned lo = (unsigned)__builtin_amdgcn_readfirstlane((int)(v & 0xffffffffull));
    unsigned hi = (unsigned)__builtin_amdgcn_readfirstlane((int)(v >> 32));
    return (((u64)hi) << 32) | lo;
}
// f32 multiset per-wave top-13: ballot single-lane elimination preserves duplicates
template<int NSL>
__device__ __forceinline__ void wave_merge_max13_f32(float (&l)[NSL], float* dst, int lane) {
    int p = 0;
    for (int r = 0; r < KTOP; ++r) {
        float cur = NEGINF;
        #pragma unroll
        for (int s = 0; s < NSL; ++s) if (s == p) cur = l[NSL - 1 - s];
        float bm = wave_max_bc_f32(cur);
        u64 m = __ballot(cur == bm && bm != NEGINF);
        int first = __ffsll(m) - 1;
        if (lane == first) p++;
        if (lane == 0) dst[r] = bm;
    }
}
// u64 per-wave top-13 min (keys idx-distinct -> single match per round)
template<int NSL>
__device__ __forceinline__ void wave_merge_minN(u64 (&l)[NSL], u64* dst, int lane) {
    int p = 0;
    for (int r = 0; r < KTOP; ++r) {
        u64 cur = ~0ull;
        #pragma unroll
        for (int s = 0; s < NSL; ++s) if (s == p) cur = l[s];
        u64 bm = wave_min_bc_u64(cur);
        if (cur == bm && bm != ~0ull) p++;
        if (lane == 0) dst[r] = bm;
    }
}

// ---------- exact formulas (verbatim: bit-identical selection) ----------
__device__ __forceinline__ float iou_exact(float4 pb, float areap, float gx1, float gy1,
                                           float gx2, float gy2, float areag) {
    float iw = fmaxf(fminf(pb.z, gx2) - fmaxf(pb.x, gx1), 0.0f);
    float ih = fmaxf(fminf(pb.w, gy2) - fmaxf(pb.y, gy1), 0.0f);
    float inter = iw * ih;
    return inter / fmaxf(areap + areag - inter, 1e-6f);
}
__device__ __forceinline__ float cost_exact(float4 p2, float gcx, float gcy,
                                            float l, float iou) {
    float dx = p2.x - gcx, dy = p2.y - gcy;
    float dist = sqrtf(dx * dx + dy * dy) / p2.z;
    float soft = exp2f((dist - 3.0f) * L10);
    float sig = 1.0f / (1.0f + expf(-l));
    float dd = iou - sig;
    float bce = fmaxf(l, 0.0f) - l * iou + log1pf(expf(-fabsf(l)));
    float iouc = -logf(iou + EPS_F) * 3.0f;
    return bce * (dd * dd) + iouc + soft;
}

// ---------- prep: int64 detect + init + valid mask + packed array + bin hists ----------
// p2 = (px, py, stride, w) where w = valid ? (stride*RFIX)^2*(1+1e-5) : -1
// Hist/max aggregation is LDS-first: per-block LDS hists + LDS atomicMax, one
// global merge per block. (Round-9 regression: 67K per-lane global atomicMax to
// ONE address serialized in the L2 atomic unit -> k_prep 49us.)
__global__ __launch_bounds__(256) void k_prep(
        const float* __restrict__ priors, const float* __restrict__ gt,
        const void* labels, const float* __restrict__ pboxes,
        float4* __restrict__ pbp,
        int* count, int* firstgt, int* flag,
        int* histI, int* histC, int* maxbuf) {
    __shared__ float4 gbox[NGT];
    __shared__ int    gpad[NGT];
    __shared__ int    bad;
    __shared__ int    lhI[NB];    // 4 KB per-block iou-center hist
    __shared__ int    lhC[NB];    // 4 KB per-block prior-point hist
    __shared__ int    lmax0, lmax1;
    const int tid = threadIdx.x;
    const int b = blockIdx.x;
    if (b == 0 && tid == 0) bad = 0;
    if (tid == 0) { lmax0 = 0; lmax1 = 0; }
    for (int t = tid; t < NB; t += 256) { lhI[t] = 0; lhC[t] = 0; }
    {
        float4 bx = ((const float4*)gt)[tid];
        gbox[tid] = bx;
        gpad[tid] = ((bx.x + bx.y + bx.z + bx.w) > 0.0f) ? 1 : 0;
    }
    __syncthreads();
    if (b == 0 && tid < 128) {
        long long v = ((const long long*)labels)[tid];   // first 1024B: in-bounds either layout
        if (v < 0 || v >= NCLS) atomicOr(&bad, 1);
    }
    int g = b * 256 + tid;
    if (g < NPRI) {
        count[g] = 0; firstgt[g] = NGT;
        float4 pr = ((const float4*)priors)[g];
        float px = pr.x, py = pr.y;
        int v = 0;
        for (int j = 0; j < NGT; ++j) {
            float4 bx = gbox[j];
            float m = fminf(fminf(px - bx.x, py - bx.y), fminf(bx.z - px, bx.w - py));
            if (m > 0.0f && gpad[j]) { v = 1; break; }
        }
        float rad = pr.z * RFIX;
        float w = v ? rad * rad * (1.0f + 1e-5f) : -1.0f;
        float4 pb = ((const float4*)pboxes)[g];
        pbp[2 * g]     = pb;
        pbp[2 * g + 1] = make_float4(px, py, pr.z, w);
        // --- LDS bin histograms + LDS max (positive-float int order) ---
        float pcx = (pb.x + pb.z) * 0.5f, pcy = (pb.y + pb.w) * 0.5f;
        atomicAdd(&lhI[bin1(pcy) * NBX + bin1(pcx)], 1);
        atomicAdd(&lhC[bin1(py) * NBX + bin1(px)], 1);
        float hw = fmaxf((pb.z - pb.x) * 0.5f, 0.0f);
        float hh = fmaxf((pb.w - pb.y) * 0.5f, 0.0f);
        atomicMax(&lmax0, __float_as_int(fmaxf(hw, hh)));
        if (v) atomicMax(&lmax1, __float_as_int(w));
    }
    __syncthreads();
    // one global merge per block: only nonzero bins, 2 atomicMax total
    for (int t = tid; t < NB; t += 256) {
        int h = lhI[t]; if (h) atomicAdd(&histI[t], h);
        h = lhC[t];     if (h) atomicAdd(&histC[t], h);
    }
    if (tid == 0) {
        atomicMax(&maxbuf[0], lmax0);
        atomicMax(&maxbuf[1], lmax1);
    }
    if (b == 0) {
        if (tid == 0) *flag = bad ? 0 : 1;   // 1 => int64 layout (bad set before first sync)
    }
}

// ---------- exclusive prefix over both 1024-bin hists (one block) ----------
__global__ __launch_bounds__(NB) void k_bins(
        const int* __restrict__ histI, const int* __restrict__ histC,
        int* startI, int* startC, int* curI, int* curC) {
    __shared__ int sc[NB];
    const int t = threadIdx.x;
    int h = histI[t];
    sc[t] = h;
    __syncthreads();
    for (int off = 1; off < NB; off <<= 1) {
        int u = (t >= off) ? sc[t - off] : 0;
        __syncthreads();
        sc[t] += u;
        __syncthreads();
    }
    int excl = sc[t] - h;
    startI[t] = excl; curI[t] = excl;
    if (t == NB - 1) startI[NB] = sc[t];
    __syncthreads();
    h = histC[t];
    sc[t] = h;
    __syncthreads();
    for (int off = 1; off < NB; off <<= 1) {
        int u = (t >= off) ? sc[t - off] : 0;
        __syncthreads();
        sc[t] += u;
        __syncthreads();
    }
    excl = sc[t] - h;
    startC[t] = excl; curC[t] = excl;
    if (t == NB - 1) startC[NB] = sc[t];
}

// ---------- scatter into bin-sorted arrays (order within bin irrelevant) ----------
__global__ __launch_bounds__(256) void k_scatter(
        const float4* __restrict__ pbp,
        int* curI, int* curC,
        float4* __restrict__ A_pb, float4* __restrict__ A_pc) {
    const int i = blockIdx.x * 256 + threadIdx.x;
    if (i >= NPRI) return;
    float4 pb = pbp[2 * i];
    float4 p2 = pbp[2 * i + 1];
    float pcx = (pb.x + pb.z) * 0.5f, pcy = (pb.y + pb.w) * 0.5f;   // identical to k_prep
    int r = atomicAdd(&curI[bin1(pcy) * NBX + bin1(pcx)], 1);
    A_pb[r] = pb;
    int r2 = atomicAdd(&curC[bin1(p2.y) * NBX + bin1(p2.x)], 1);
    A_pc[r2] = make_float4(p2.x, p2.y, p2.w, __int_as_float(i));   // (px,py,w,idx bits)
}

// ---------- one 512-thr block per GT: BINNED collects + exact merges ----------
// Tested sets are provable supersets (margins M=2*hmax+1, rmax=sqrt(wmax)+1 from
// data maxima; floor+clamp monotone => range inclusion). Membership predicates
// unchanged => collected sets bit-identical to the full scan. Fallbacks (fI,
// mode-1, mode-2) remain exact full-range scans.
__global__ __launch_bounds__(SCN_T) void k_scan(
        const float* __restrict__ scores,
        const float4* __restrict__ pbp,
        const float4* __restrict__ A_pb, const float4* __restrict__ A_pc,
        const int* __restrict__ startI, const int* __restrict__ startC,
        const int* __restrict__ maxbuf,
        const float* __restrict__ gt, const void* labels, const int* flag,
        int* count, int* firstgt) {
    const int tid = threadIdx.x, lane = tid & 63, wid = tid >> 6;
    const int j = blockIdx.x;
    const int is64 = *flag;

    const float4 gb = ((const float4*)gt)[j];
    const float gx1 = gb.x, gy1 = gb.y, gx2 = gb.z, gy2 = gb.w;
    const float areag = (gx2 - gx1) * (gy2 - gy1);
    const float gcx = (gx1 + gx2) * 0.5f, gcy = (gy1 + gy2) * 0.5f;
    const int lab = get_label(labels, j, is64);
    const float hmax = __int_as_float(maxbuf[0]);
    const float wmax = __int_as_float(maxbuf[1]);
    const float M = 2.0f * hmax + 1.0f;                    // iou coverage margin
    const float rmax = sqrtf(fmaxf(wmax, 0.0f)) + 1.0f;    // ball coverage margin

    __shared__ int s_ni, s_nc, s_mode;
    __shared__ float s_dmax;
    __shared__ float liou[CAPI];
    __shared__ int lcost[CAPC];
    __shared__ float wiof[(NW - 1) * KTOP];   // 7 partial iou lists (waves 1..7)
    __shared__ u64 wco[NW * KTOP];            // mode-2 fallback only
    __shared__ u64 csel[KTOP];
    __shared__ float s_iou13[KTOP];
    if (tid == 0) { s_ni = 0; s_nc = 0; }
    __syncthreads();

    // ---- binned iou collect: bins covering pred-centers in [g-M, g+M] ----
    {
        int lox = bin1(gx1 - M), hix = bin1(gx2 + M);
        int loy = bin1(gy1 - M), hiy = bin1(gy2 + M);
        for (int by = loy; by <= hiy; ++by) {
            int s0 = startI[by * NBX + lox];
            int e0 = startI[by * NBX + hix + 1];
            for (int r = s0 + tid; r < e0; r += SCN_T) {
                float4 pb = A_pb[r];
                float areap = (pb.z - pb.x) * (pb.w - pb.y);
                float iou = iou_exact(pb, areap, gx1, gy1, gx2, gy2, areag);
                if (iou > 0.0f) {
                    int p = atomicAdd(&s_ni, 1);
                    if (p < CAPI) liou[p] = iou;
                }
            }
        }
    }
    // ---- binned cost collect: bins covering prior points in gc +- rmax ----
    {
        int lox = bin1(gcx - rmax), hix = bin1(gcx + rmax);
        int loy = bin1(gcy - rmax), hiy = bin1(gcy + rmax);
        for (int by = loy; by <= hiy; ++by) {
            int s0 = startC[by * NBX + lox];
            int e0 = startC[by * NBX + hix + 1];
            for (int r = s0 + tid; r < e0; r += SCN_T) {
                float4 pc = A_pc[r];                 // (px,py,w,idx)
                float dx = pc.x - gcx, dy = pc.y - gcy;
                if (dx * dx + dy * dy <= pc.z) {     // w=-1 invalid never passes
                    int p = atomicAdd(&s_nc, 1);
                    if (p < CAPC) lcost[p] = __float_as_int(pc.w);
                }
            }
        }
    }
    __syncthreads();
    const int ni = s_ni, nc = s_nc;
    const int ncc = (nc < CAPC) ? nc : CAPC;
    const bool fI = (ni > CAPI);

    // ---- phase 1: wave 0 = cost merge; waves 1..7 = iou partial merges ----
    if (wid == 0) {
        u64 lf[KTOP];
        #pragma unroll
        for (int s = 0; s < KTOP; ++s) lf[s] = ~0ull;
        for (int k = lane; k < ncc; k += 64) {   // <=16 per lane; 13-deep list complete
            int i = lcost[k];
            float4 pb = pbp[2 * i];
            float4 p2 = pbp[2 * i + 1];
            float areap = (pb.z - pb.x) * (pb.w - pb.y);
            float iou = iou_exact(pb, areap, gx1, gy1, gx2, gy2, areag);
            float ec = cost_exact(p2, gcx, gcy, scores[(size_t)i * NCLS + lab], iou);
            u64 ck = (((u64)__float_as_uint(ec)) << 32) | (unsigned)i;
            if (ck < lf[KTOP - 1]) {
                lf[KTOP - 1] = ck;
                #pragma unroll
                for (int s = KTOP - 1; s > 0; --s)
                    if (lf[s] < lf[s - 1]) { u64 t = lf[s]; lf[s] = lf[s - 1]; lf[s - 1] = t; }
            }
        }
        wave_merge_minN<KTOP>(lf, csel, lane);
        if (lane == 0) {
            u64 tk = csel[KTOP - 1];
            int mode; float dmax = 0.0f;
            if (tk == ~0ull) mode = 2;               // <13 candidates in RFIX ball
            else {
                float tau = __uint_as_float((unsigned)(tk >> 32));
                if (!(tau < 9.0e7f)) mode = 2;       // INF-ambiguity zone
                else {
                    dmax = 3.0f + __log2f(tau + 1e-5f) * (1.0f / L10) + 4e-3f;
                    mode = (dmax > RFIX || nc > CAPC) ? 1 : 0;
                }
            }
            s_mode = mode; s_dmax = dmax;
        }
    } else if (!fI) {
        float lf[KTOP];
        #pragma unroll
        for (int s = 0; s < KTOP; ++s) lf[s] = NEGINF;
        int nn = (ni < CAPI) ? ni : CAPI;
        for (int k = (wid - 1) * 64 + lane; k < nn; k += 64 * (NW - 1)) {
            float v = liou[k];
            if (v > lf[0]) {
                lf[0] = v;
                #pragma unroll
                for (int s = 0; s < KTOP - 1; ++s)
                    if (lf[s] > lf[s + 1]) { float t = lf[s]; lf[s] = lf[s + 1]; lf[s + 1] = t; }
            }
        }
        wave_merge_max13_f32<KTOP>(lf, &wiof[(wid - 1) * KTOP], lane);
    }
    __syncthreads();

    if (fI) {   // rare: iou list overflowed -> exact full rescan by waves 1..7
        if (wid > 0) {
            float lf[KTOP];
            #pragma unroll
            for (int s = 0; s < KTOP; ++s) lf[s] = NEGINF;
            for (int i = (wid - 1) * 64 + lane; i < NPRI; i += 64 * (NW - 1)) {
                float4 pb = pbp[2 * i];
                float areap = (pb.z - pb.x) * (pb.w - pb.y);
                float iou = iou_exact(pb, areap, gx1, gy1, gx2, gy2, areag);
                if (iou > 0.0f && iou > lf[0]) {
                    lf[0] = iou;
                    #pragma unroll
                    for (int s = 0; s < KTOP - 1; ++s)
                        if (lf[s] > lf[s + 1]) { float t = lf[s]; lf[s] = lf[s + 1]; lf[s + 1] = t; }
                }
            }
            wave_merge_max13_f32<KTOP>(lf, &wiof[(wid - 1) * KTOP], lane);
        }
        __syncthreads();
    }

    // ---- cross-merge the 7 iou lists -> s_iou13 (descending, multiset) ----
    if (wid == 0) {
        int p = 0;
        for (int r = 0; r < KTOP; ++r) {
            float cur = (lane < NW - 1 && p < KTOP) ? wiof[lane * KTOP + p] : NEGINF;
            float bm = wave_max_bc_f32(cur);
            u64 m = __ballot(cur == bm && bm != NEGINF);
            int first = __ffsll(m) - 1;
            if (lane == first) p++;
            if (lane == 0) s_iou13[r] = bm;
        }
    }

    int mode = s_mode;
    if (mode == 1) {   // re-collect at the sound radius Dmax' (rare, exact full scan)
        const float dmax = s_dmax;
        if (tid == 0) s_nc = 0;
        __syncthreads();
        for (int i = tid; i < NPRI; i += SCN_T) {
            float4 p2 = pbp[2 * i + 1];
            if (p2.w > 0.0f) {
                float dx = p2.x - gcx, dy = p2.y - gcy;
                float rad = p2.z * dmax;
                if (dx * dx + dy * dy <= rad * rad * (1.0f + 1e-5f)) {
                    int p = atomicAdd(&s_nc, 1);
                    if (p < CAPC) lcost[p] = i;
                }
            }
        }
        __syncthreads();
        int nc2 = s_nc;
        if (nc2 <= CAPC) {
            if (wid == 0) {
                u64 lf[KTOP];
                #pragma unroll
                for (int s = 0; s < KTOP; ++s) lf[s] = ~0ull;
                for (int k = lane; k < nc2; k += 64) {
                    int i = lcost[k];
                    float4 pb = pbp[2 * i];
                    float4 p2 = pbp[2 * i + 1];
                    float areap = (pb.z - pb.x) * (pb.w - pb.y);
                    float iou = iou_exact(pb, areap, gx1, gy1, gx2, gy2, areag);
                    float ec = cost_exact(p2, gcx, gcy, scores[(size_t)i * NCLS + lab], iou);
                    u64 ck = (((u64)__float_as_uint(ec)) << 32) | (unsigned)i;
                    if (ck < lf[KTOP - 1]) {
                        lf[KTOP - 1] = ck;
                        #pragma unroll
                        for (int s = KTOP - 1; s > 0; --s)
                            if (lf[s] < lf[s - 1]) { u64 t = lf[s]; lf[s] = lf[s - 1]; lf[s - 1] = t; }
                    }
                }
                wave_merge_minN<KTOP>(lf, csel, lane);
            }
        } else {
            mode = 2;   // uniform (s_nc shared)
        }
        __syncthreads();
    }
    if (mode == 2) {   // exact full scan (correctness net)
        u64 lf[KTOP];
        #pragma unroll
        for (int s = 0; s < KTOP; ++s) lf[s] = ~0ull;
        for (int i = tid; i < NPRI; i += SCN_T) {
            float4 pb = pbp[2 * i];
            float4 p2 = pbp[2 * i + 1];
            float areap = (pb.z - pb.x) * (pb.w - pb.y);
            float iou = iou_exact(pb, areap, gx1, gy1, gx2, gy2, areag);
            float ec = INF_F;
            if (p2.w > 0.0f) ec = cost_exact(p2, gcx, gcy, scores[(size_t)i * NCLS + lab], iou);
            u64 k2 = (((u64)__float_as_uint(ec)) << 32) | (unsigned)i;
            if (k2 < lf[KTOP - 1]) {
                lf[KTOP - 1] = k2;
                #pragma unroll
                for (int s = KTOP - 1; s > 0; --s)
                    if (lf[s] < lf[s - 1]) { u64 t = lf[s]; lf[s] = lf[s - 1]; lf[s - 1] = t; }
            }
        }
        wave_merge_minN<KTOP>(lf, &wco[wid * KTOP], lane);
        __syncthreads();
        if (wid == 0) {
            int p = 0;
            for (int r = 0; r < KTOP; ++r) {
                u64 cur = (lane < NW && p < KTOP) ? wco[lane * KTOP + p] : ~0ull;
                u64 bm = wave_min_bc_u64(cur);
                if (cur == bm && bm != ~0ull) p++;
                if (lane == 0) csel[r] = bm;
            }
        }
        __syncthreads();
    }

    // ---- finalize: ks from descending iou sum; scatter selections ----
    __syncthreads();
    if (wid == 0) {
        float tsum = 0.0f;
        #pragma unroll
        for (int r = 0; r < KTOP; ++r) {
            float v = s_iou13[r];
            tsum += (v == NEGINF) ? 0.0f : v;   // descending-order sum (missing = 0, as ref)
        }
        int ks = (int)tsum;
        if (ks < 1) ks = 1;
        if (lane < KTOP && lane < ks) {
            u64 mine = csel[lane];
            if (mine != ~0ull) {
                int idx = (int)(unsigned)(mine & 0xFFFFFFFFull);
                atomicAdd(&count[idx], 1);
                atomicMin(&firstgt[idx], j);
            }
        }
    }
}

// ---------- per-prior finalize; multi-matched priors resolved in-block ----------
__global__ __launch_bounds__(256) void k_assign(
        const float* __restrict__ scores,
        const float4* __restrict__ pbp, const float* __restrict__ gt,
        const void* labels, const int* flag,
        const int* __restrict__ count, const int* __restrict__ firstgt,
        float* __restrict__ out) {
    __shared__ float4 gbox[NGT];
    __shared__ int glab[NGT];
    __shared__ float gcxs[NGT], gcys[NGT], gareas[NGT];
    __shared__ int s_nm;
    __shared__ int s_mlist[256];
    __shared__ u64 red4[4];
    const int tid = threadIdx.x;
    const int is64 = *flag;
    {
        float4 b = ((const float4*)gt)[tid];
        gbox[tid] = b;
        glab[tid] = get_label(labels, tid, is64);
        gcxs[tid] = (b.x + b.z) * 0.5f;
        gcys[tid] = (b.y + b.w) * 0.5f;
        gareas[tid] = (b.z - b.x) * (b.w - b.y);
    }
    if (tid == 0) s_nm = 0;
    __syncthreads();
    const int i = blockIdx.x * 256 + tid;
    const bool act = (i < NPRI);
    if (act) {
        float4 p2 = pbp[2 * i + 1];
        int v = (p2.w > 0.0f) ? 1 : 0;
        int c = count[i];
        float o0 = 0.0f, o1 = -INF_F, o2 = -1.0f;
        if (v && c == 1) {
            int j = firstgt[i];
            float4 pb = pbp[2 * i];
            float areap = (pb.z - pb.x) * (pb.w - pb.y);
            float4 g = gbox[j];
            float iw = fmaxf(fminf(pb.z, g.z) - fmaxf(pb.x, g.x), 0.0f);
            float ih = fmaxf(fminf(pb.w, g.w) - fmaxf(pb.y, g.y), 0.0f);
            float inter = iw * ih;
            float iou = inter / fmaxf(areap + gareas[j] - inter, 1e-6f);
            o0 = (float)(j + 1); o1 = iou; o2 = (float)glab[j];
        } else if (v && c > 1) {
            int p = atomicAdd(&s_nm, 1);
            s_mlist[p] = i;
        }
        out[i] = o0;
        out[NPRI + i] = o1;
        out[2 * NPRI + i] = o2;
    }
    __syncthreads();
    // ---- in-block multi resolution: one GT per thread, block argmin per prior ----
    const int nm = s_nm;
    const int j = tid;
    for (int m = 0; m < nm; ++m) {
        const int ii = s_mlist[m];
        float4 pb = pbp[2 * ii];
        float4 p2 = pbp[2 * ii + 1];
        float areap = (pb.z - pb.x) * (pb.w - pb.y);

        float4 g = gbox[j];
        float iw = fmaxf(fminf(pb.z, g.z) - fmaxf(pb.x, g.x), 0.0f);
        float ih = fmaxf(fminf(pb.w, g.w) - fmaxf(pb.y, g.y), 0.0f);
        float inter = iw * ih;
        float iou = inter / fmaxf(areap + gareas[j] - inter, 1e-6f);
        float dx = p2.x - gcxs[j], dy = p2.y - gcys[j];
        float dist = sqrtf(dx * dx + dy * dy) / p2.z;
        float soft = exp2f((dist - 3.0f) * L10);
        float l = scores[(size_t)ii * NCLS + glab[j]];
        float sig = 1.0f / (1.0f + expf(-l));
        float dd = iou - sig;
        float bce = fmaxf(l, 0.0f) - l * iou + log1pf(expf(-fabsf(l)));
        float cost = bce * (dd * dd) + (-logf(iou + EPS_F) * 3.0f) + soft;

        u64 key = (((u64)__float_as_uint(cost)) << 32) | (unsigned)j;
        u64 v = key;
        #pragma unroll
        for (int off = 32; off > 0; off >>= 1) {
            u64 o = __shfl_down(v, off, 64);
            v = (o < v) ? o : v;
        }
        if ((tid & 63) == 0) red4[tid >> 6] = v;
        __syncthreads();
        u64 best = red4[0];
        #pragma unroll
        for (int q = 1; q < 4; ++q) best = (red4[q] < best) ? red4[q] : best;
        if (key == best) {
            out[ii] = (float)(j + 1);
            out[NPRI + ii] = iou;
            out[2 * NPRI + ii] = (float)glab[j];
        }
        __syncthreads();
    }
}

extern "C" void kernel_launch(void* const* d_in, const int* in_sizes, int n_in,
                              void* d_out, int out_size, void* d_ws, size_t ws_size,
                              hipStream_t stream) {
    const float* scores = (const float*)d_in[0];
    const float* priors = (const float*)d_in[1];
    const float* pboxes = (const float*)d_in[2];
    const float* gt     = (const float*)d_in[3];
    const void*  labels = d_in[4];
    float* out = (float*)d_out;

    char* ws = (char*)d_ws;
    size_t off = 0;
    auto alloc = [&](size_t bytes) { size_t o = off; off = (off + bytes + 255) & ~(size_t)255; return o; };
    int*    flag    = (int*)(ws + alloc(4));
    int*    count   = (int*)(ws + alloc((size_t)NPRI * 4));
    int*    firstgt = (int*)(ws + alloc((size_t)NPRI * 4));
    int*    histI   = (int*)(ws + alloc((size_t)(2 * NB + 2) * 4));   // histI|histC|maxbuf contiguous
    int*    histC   = histI + NB;
    int*    maxbuf  = histI + 2 * NB;
    int*    startI  = (int*)(ws + alloc((size_t)(NB + 1) * 4));
    int*    startC  = (int*)(ws + alloc((size_t)(NB + 1) * 4));
    int*    curI    = (int*)(ws + alloc((size_t)NB * 4));
    int*    curC    = (int*)(ws + alloc((size_t)NB * 4));
    float4* pbp     = (float4*)(ws + alloc((size_t)NPRI * 32));
    float4* A_pb    = (float4*)(ws + alloc((size_t)NPRI * 16));
    float4* A_pc    = (float4*)(ws + alloc((size_t)NPRI * 16));
    (void)ws_size;

    hipMemsetAsync(histI, 0, (size_t)(2 * NB + 2) * 4, stream);   // hists + max slots
    hipLaunchKernelGGL(k_prep, dim3(PREP_BLKS), dim3(256), 0, stream,
                       priors, gt, labels, pboxes, pbp, count, firstgt, flag,
                       histI, histC, maxbuf);
    hipLaunchKernelGGL(k_bins, dim3(1), dim3(NB), 0, stream,
                       histI, histC, startI, startC, curI, curC);
    hipLaunchKernelGGL(k_scatter, dim3(PREP_BLKS), dim3(256), 0, stream,
                       pbp, curI, curC, A_pb, A_pc);
    hipLaunchKernelGGL(k_scan, dim3(NGT), dim3(SCN_T), 0, stream,
                       scores, pbp, A_pb, A_pc, startI, startC, maxbuf,
                       gt, labels, flag, count, firstgt);
    hipLaunchKernelGGL(k_assign, dim3((NPRI + 255) / 256), dim3(256), 0, stream,
                       scores, pbp, gt, labels, flag, count, firstgt, out);
}

// Round 11
// 133.697 us; speedup vs baseline: 1.2384x; 1.1743x over previous
//
#include <hip/hip_runtime.h>
#include <cstdint>

#define NPRI 33600
#define NGT  256
#define NCLS 80
#define KTOP 13
#define INF_F 1.0e8f
#define EPS_F 1e-7f
#define L10 3.3219280948873623f
#define SCN_T 512
#define NW   (SCN_T / 64)          // 8 waves per block
#define CAPI 4096                  // per-GT positive-iou values
#define CAPC 1024                  // per-GT cost candidates
#define RFIX 5.5f                  // fixed collect radius (strides)
#define NBX  32                    // 32x32 spatial bins (32px at IMG=1024)
#define NB   (NBX * NBX)
#define PREP_BLKS ((NPRI + 255) / 256)
#define VAL_BLKS (NPRI / 4)        // k_valid: 4 priors per 256-thr block (wave-per-prior)
#define NEGINF __int_as_float(0xff800000)

typedef unsigned long long u64;

__device__ __forceinline__ int get_label(const void* p, int j, int is64) {
    if (is64) return (int)((const long long*)p)[j];
    return ((const int*)p)[j];
}

// bin of a coordinate: floor(c/32) clamped. Monotone floor+clamp => for any
// lo <= c <= hi, bin(c) in [bin(lo), bin(hi)] — coverage holds for ANY range.
// MUST be byte-identical in k_prep (hist) and k_scatter (placement).
__device__ __forceinline__ int bin1(float c) {
    int b = (int)floorf(c * 0.03125f);
    return b < 0 ? 0 : (b > NBX - 1 ? NBX - 1 : b);
}

// ---------- wave helpers (reduce + broadcast) ----------
__device__ __forceinline__ float wave_max_bc_f32(float v) {
    #pragma unroll
    for (int off = 32; off > 0; off >>= 1) v = fmaxf(v, __shfl_down(v, off, 64));
    return __int_as_float(__builtin_amdgcn_readfirstlane(__float_as_int(v)));
}
__device__ __forceinline__ u64 wave_min_bc_u64(u64 v) {
    #pragma unroll
    for (int off = 32; off > 0; off >>= 1) { u64 o = __shfl_down(v, off, 64); v = (o < v) ? o : v; }
    unsigned lo = (unsigned)__builtin_amdgcn_readfirstlane((int)(v & 0xffffffffull));
    unsigned hi = (unsigned)__builtin_amdgcn_readfirstlane((int)(v >> 32));
    return (((u64)hi) << 32) | lo;
}
// f32 multiset per-wave top-13: ballot single-lane elimination preserves duplicates
template<int NSL>
__device__ __forceinline__ void wave_merge_max13_f32(float (&l)[NSL], float* dst, int lane) {
    int p = 0;
    for (int r = 0; r < KTOP; ++r) {
        float cur = NEGINF;
        #pragma unroll
        for (int s = 0; s < NSL; ++s) if (s == p) cur = l[NSL - 1 - s];
        float bm = wave_max_bc_f32(cur);
        u64 m = __ballot(cur == bm && bm != NEGINF);
        int first = __ffsll(m) - 1;
        if (lane == first) p++;
        if (lane == 0) dst[r] = bm;
    }
}
// u64 per-wave top-13 min (keys idx-distinct -> single match per round)
template<int NSL>
__device__ __forceinline__ void wave_merge_minN(u64 (&l)[NSL], u64* dst, int lane) {
    int p = 0;
    for (int r = 0; r < KTOP; ++r) {
        u64 cur = ~0ull;
        #pragma unroll
        for (int s = 0; s < NSL; ++s) if (s == p) cur = l[s];
        u64 bm = wave_min_bc_u64(cur);
        if (cur == bm && bm != ~0ull) p++;
        if (lane == 0) dst[r] = bm;
    }
}

// ---------- exact formulas (verbatim: bit-identical selection) ----------
__device__ __forceinline__ float iou_exact(float4 pb, float areap, float gx1, float gy1,
                                           float gx2, float gy2, float areag) {
    float iw = fmaxf(fminf(pb.z, gx2) - fmaxf(pb.x, gx1), 0.0f);
    float ih = fmaxf(fminf(pb.w, gy2) - fmaxf(pb.y, gy1), 0.0f);
    float inter = iw * ih;
    return inter / fmaxf(areap + areag - inter, 1e-6f);
}
__device__ __forceinline__ float cost_exact(float4 p2, float gcx, float gcy,
                                            float l, float iou) {
    float dx = p2.x - gcx, dy = p2.y - gcy;
    float dist = sqrtf(dx * dx + dy * dy) / p2.z;
    float soft = exp2f((dist - 3.0f) * L10);
    float sig = 1.0f / (1.0f + expf(-l));
    float dd = iou - sig;
    float bce = fmaxf(l, 0.0f) - l * iou + log1pf(expf(-fabsf(l)));
    float iouc = -logf(iou + EPS_F) * 3.0f;
    return bce * (dd * dd) + iouc + soft;
}

// ---------- valid mask: ONE WAVE PER PRIOR (round-10 lesson: the per-thread
// 256-GT loop was ~40us all session — 528 waves, 1/SIMD, dependent-load chain,
// no early exit at wave level). Here: lane l tests GTs {l,l+64,l+128,l+192},
// ballot-OR. 33600 waves, 4 unrolled ILP loads, ~3us. Predicate + pad FP order
// byte-identical to ref => valid[] bit-identical. ----------
__global__ __launch_bounds__(256) void k_valid(
        const float* __restrict__ priors, const float* __restrict__ gt,
        int* __restrict__ valid) {
    const int lane = threadIdx.x & 63, wid = threadIdx.x >> 6;
    const int i = blockIdx.x * 4 + wid;          // < NPRI (VAL_BLKS*4 == NPRI)
    const float px = priors[4 * i];
    const float py = priors[4 * i + 1];
    bool hit = false;
    #pragma unroll
    for (int q = 0; q < 4; ++q) {
        float4 bx = ((const float4*)gt)[lane + 64 * q];
        float pad = bx.x + bx.y + bx.z + bx.w;   // ref sum order
        float m = fminf(fminf(px - bx.x, py - bx.y), fminf(bx.z - px, bx.w - py));
        hit |= (m > 0.0f && pad > 0.0f);
    }
    u64 msk = __ballot(hit);
    if (lane == 0) valid[i] = (msk != 0ull) ? 1 : 0;
}

// ---------- prep: int64 detect + init + packed array + LDS bin hists ----------
// p2 = (px, py, stride, w) where w = valid ? (stride*RFIX)^2*(1+1e-5) : -1
__global__ __launch_bounds__(256) void k_prep(
        const float* __restrict__ priors,
        const void* labels, const float* __restrict__ pboxes,
        const int* __restrict__ valid,
        float4* __restrict__ pbp,
        int* count, int* firstgt, int* flag,
        int* histI, int* histC, int* maxbuf) {
    __shared__ int bad;
    __shared__ int lhI[NB];    // 4 KB per-block iou-center hist
    __shared__ int lhC[NB];    // 4 KB per-block prior-point hist
    __shared__ int lmax0, lmax1;
    const int tid = threadIdx.x;
    const int b = blockIdx.x;
    if (b == 0 && tid == 0) bad = 0;
    if (tid == 0) { lmax0 = 0; lmax1 = 0; }
    for (int t = tid; t < NB; t += 256) { lhI[t] = 0; lhC[t] = 0; }
    __syncthreads();
    if (b == 0 && tid < 128) {
        long long v = ((const long long*)labels)[tid];   // first 1024B: in-bounds either layout
        if (v < 0 || v >= NCLS) atomicOr(&bad, 1);
    }
    int g = b * 256 + tid;
    if (g < NPRI) {
        count[g] = 0; firstgt[g] = NGT;
        float4 pr = ((const float4*)priors)[g];
        float px = pr.x, py = pr.y;
        int v = valid[g];
        float rad = pr.z * RFIX;
        float w = v ? rad * rad * (1.0f + 1e-5f) : -1.0f;
        float4 pb = ((const float4*)pboxes)[g];
        pbp[2 * g]     = pb;
        pbp[2 * g + 1] = make_float4(px, py, pr.z, w);
        // --- LDS bin histograms + LDS max (positive-float int order) ---
        float pcx = (pb.x + pb.z) * 0.5f, pcy = (pb.y + pb.w) * 0.5f;
        atomicAdd(&lhI[bin1(pcy) * NBX + bin1(pcx)], 1);
        atomicAdd(&lhC[bin1(py) * NBX + bin1(px)], 1);
        float hw = fmaxf((pb.z - pb.x) * 0.5f, 0.0f);
        float hh = fmaxf((pb.w - pb.y) * 0.5f, 0.0f);
        atomicMax(&lmax0, __float_as_int(fmaxf(hw, hh)));
        if (v) atomicMax(&lmax1, __float_as_int(w));
    }
    __syncthreads();
    // one global merge per block: only nonzero bins, 2 atomicMax total
    for (int t = tid; t < NB; t += 256) {
        int h = lhI[t]; if (h) atomicAdd(&histI[t], h);
        h = lhC[t];     if (h) atomicAdd(&histC[t], h);
    }
    if (tid == 0) {
        atomicMax(&maxbuf[0], lmax0);
        atomicMax(&maxbuf[1], lmax1);
    }
    if (b == 0 && tid == 0) *flag = bad ? 0 : 1;   // 1 => int64 layout
}

// ---------- exclusive prefix over both 1024-bin hists (one block) ----------
__global__ __launch_bounds__(NB) void k_bins(
        const int* __restrict__ histI, const int* __restrict__ histC,
        int* startI, int* startC, int* curI, int* curC) {
    __shared__ int sc[NB];
    const int t = threadIdx.x;
    int h = histI[t];
    sc[t] = h;
    __syncthreads();
    for (int off = 1; off < NB; off <<= 1) {
        int u = (t >= off) ? sc[t - off] : 0;
        __syncthreads();
        sc[t] += u;
        __syncthreads();
    }
    int excl = sc[t] - h;
    startI[t] = excl; curI[t] = excl;
    if (t == NB - 1) startI[NB] = sc[t];
    __syncthreads();
    h = histC[t];
    sc[t] = h;
    __syncthreads();
    for (int off = 1; off < NB; off <<= 1) {
        int u = (t >= off) ? sc[t - off] : 0;
        __syncthreads();
        sc[t] += u;
        __syncthreads();
    }
    excl = sc[t] - h;
    startC[t] = excl; curC[t] = excl;
    if (t == NB - 1) startC[NB] = sc[t];
}

// ---------- scatter into bin-sorted arrays (order within bin irrelevant) ----------
__global__ __launch_bounds__(256) void k_scatter(
        const float4* __restrict__ pbp,
        int* curI, int* curC,
        float4* __restrict__ A_pb, float4* __restrict__ A_pc) {
    const int i = blockIdx.x * 256 + threadIdx.x;
    if (i >= NPRI) return;
    float4 pb = pbp[2 * i];
    float4 p2 = pbp[2 * i + 1];
    float pcx = (pb.x + pb.z) * 0.5f, pcy = (pb.y + pb.w) * 0.5f;   // identical to k_prep
    int r = atomicAdd(&curI[bin1(pcy) * NBX + bin1(pcx)], 1);
    A_pb[r] = pb;
    int r2 = atomicAdd(&curC[bin1(p2.y) * NBX + bin1(p2.x)], 1);
    A_pc[r2] = make_float4(p2.x, p2.y, p2.w, __int_as_float(i));   // (px,py,w,idx bits)
}

// ---------- one 512-thr block per GT: BINNED collects + exact merges ----------
// Tested sets are provable supersets (margins M=2*hmax+1, rmax=sqrt(wmax)+1 from
// data maxima; floor+clamp monotone => range inclusion). Membership predicates
// unchanged => collected sets bit-identical to the full scan. Fallbacks (fI,
// mode-1, mode-2) remain exact full-range scans.
__global__ __launch_bounds__(SCN_T) void k_scan(
        const float* __restrict__ scores,
        const float4* __restrict__ pbp,
        const float4* __restrict__ A_pb, const float4* __restrict__ A_pc,
        const int* __restrict__ startI, const int* __restrict__ startC,
        const int* __restrict__ maxbuf,
        const float* __restrict__ gt, const void* labels, const int* flag,
        int* count, int* firstgt) {
    const int tid = threadIdx.x, lane = tid & 63, wid = tid >> 6;
    const int j = blockIdx.x;
    const int is64 = *flag;

    const float4 gb = ((const float4*)gt)[j];
    const float gx1 = gb.x, gy1 = gb.y, gx2 = gb.z, gy2 = gb.w;
    const float areag = (gx2 - gx1) * (gy2 - gy1);
    const float gcx = (gx1 + gx2) * 0.5f, gcy = (gy1 + gy2) * 0.5f;
    const int lab = get_label(labels, j, is64);
    const float hmax = __int_as_float(maxbuf[0]);
    const float wmax = __int_as_float(maxbuf[1]);
    const float M = 2.0f * hmax + 1.0f;                    // iou coverage margin
    const float rmax = sqrtf(fmaxf(wmax, 0.0f)) + 1.0f;    // ball coverage margin

    __shared__ int s_ni, s_nc, s_mode;
    __shared__ float s_dmax;
    __shared__ float liou[CAPI];
    __shared__ int lcost[CAPC];
    __shared__ float wiof[(NW - 1) * KTOP];   // 7 partial iou lists (waves 1..7)
    __shared__ u64 wco[NW * KTOP];            // mode-2 fallback only
    __shared__ u64 csel[KTOP];
    __shared__ float s_iou13[KTOP];
    if (tid == 0) { s_ni = 0; s_nc = 0; }
    __syncthreads();

    // ---- binned iou collect: bins covering pred-centers in [g-M, g+M] ----
    {
        int lox = bin1(gx1 - M), hix = bin1(gx2 + M);
        int loy = bin1(gy1 - M), hiy = bin1(gy2 + M);
        for (int by = loy; by <= hiy; ++by) {
            int s0 = startI[by * NBX + lox];
            int e0 = startI[by * NBX + hix + 1];
            for (int r = s0 + tid; r < e0; r += SCN_T) {
                float4 pb = A_pb[r];
                float areap = (pb.z - pb.x) * (pb.w - pb.y);
                float iou = iou_exact(pb, areap, gx1, gy1, gx2, gy2, areag);
                if (iou > 0.0f) {
                    int p = atomicAdd(&s_ni, 1);
                    if (p < CAPI) liou[p] = iou;
                }
            }
        }
    }
    // ---- binned cost collect: bins covering prior points in gc +- rmax ----
    {
        int lox = bin1(gcx - rmax), hix = bin1(gcx + rmax);
        int loy = bin1(gcy - rmax), hiy = bin1(gcy + rmax);
        for (int by = loy; by <= hiy; ++by) {
            int s0 = startC[by * NBX + lox];
            int e0 = startC[by * NBX + hix + 1];
            for (int r = s0 + tid; r < e0; r += SCN_T) {
                float4 pc = A_pc[r];                 // (px,py,w,idx)
                float dx = pc.x - gcx, dy = pc.y - gcy;
                if (dx * dx + dy * dy <= pc.z) {     // w=-1 invalid never passes
                    int p = atomicAdd(&s_nc, 1);
                    if (p < CAPC) lcost[p] = __float_as_int(pc.w);
                }
            }
        }
    }
    __syncthreads();
    const int ni = s_ni, nc = s_nc;
    const int ncc = (nc < CAPC) ? nc : CAPC;
    const bool fI = (ni > CAPI);

    // ---- phase 1: wave 0 = cost merge; waves 1..7 = iou partial merges ----
    if (wid == 0) {
        u64 lf[KTOP];
        #pragma unroll
        for (int s = 0; s < KTOP; ++s) lf[s] = ~0ull;
        for (int k = lane; k < ncc; k += 64) {   // <=16 per lane; 13-deep list complete
            int i = lcost[k];
            float4 pb = pbp[2 * i];
            float4 p2 = pbp[2 * i + 1];
            float areap = (pb.z - pb.x) * (pb.w - pb.y);
            float iou = iou_exact(pb, areap, gx1, gy1, gx2, gy2, areag);
            float ec = cost_exact(p2, gcx, gcy, scores[(size_t)i * NCLS + lab], iou);
            u64 ck = (((u64)__float_as_uint(ec)) << 32) | (unsigned)i;
            if (ck < lf[KTOP - 1]) {
                lf[KTOP - 1] = ck;
                #pragma unroll
                for (int s = KTOP - 1; s > 0; --s)
                    if (lf[s] < lf[s - 1]) { u64 t = lf[s]; lf[s] = lf[s - 1]; lf[s - 1] = t; }
            }
        }
        wave_merge_minN<KTOP>(lf, csel, lane);
        if (lane == 0) {
            u64 tk = csel[KTOP - 1];
            int mode; float dmax = 0.0f;
            if (tk == ~0ull) mode = 2;               // <13 candidates in RFIX ball
            else {
                float tau = __uint_as_float((unsigned)(tk >> 32));
                if (!(tau < 9.0e7f)) mode = 2;       // INF-ambiguity zone
                else {
                    dmax = 3.0f + __log2f(tau + 1e-5f) * (1.0f / L10) + 4e-3f;
                    mode = (dmax > RFIX || nc > CAPC) ? 1 : 0;
                }
            }
            s_mode = mode; s_dmax = dmax;
        }
    } else if (!fI) {
        float lf[KTOP];
        #pragma unroll
        for (int s = 0; s < KTOP; ++s) lf[s] = NEGINF;
        int nn = (ni < CAPI) ? ni : CAPI;
        for (int k = (wid - 1) * 64 + lane; k < nn; k += 64 * (NW - 1)) {
            float v = liou[k];
            if (v > lf[0]) {
                lf[0] = v;
                #pragma unroll
                for (int s = 0; s < KTOP - 1; ++s)
                    if (lf[s] > lf[s + 1]) { float t = lf[s]; lf[s] = lf[s + 1]; lf[s + 1] = t; }
            }
        }
        wave_merge_max13_f32<KTOP>(lf, &wiof[(wid - 1) * KTOP], lane);
    }
    __syncthreads();

    if (fI) {   // rare: iou list overflowed -> exact full rescan by waves 1..7
        if (wid > 0) {
            float lf[KTOP];
            #pragma unroll
            for (int s = 0; s < KTOP; ++s) lf[s] = NEGINF;
            for (int i = (wid - 1) * 64 + lane; i < NPRI; i += 64 * (NW - 1)) {
                float4 pb = pbp[2 * i];
                float areap = (pb.z - pb.x) * (pb.w - pb.y);
                float iou = iou_exact(pb, areap, gx1, gy1, gx2, gy2, areag);
                if (iou > 0.0f && iou > lf[0]) {
                    lf[0] = iou;
                    #pragma unroll
                    for (int s = 0; s < KTOP - 1; ++s)
                        if (lf[s] > lf[s + 1]) { float t = lf[s]; lf[s] = lf[s + 1]; lf[s + 1] = t; }
                }
            }
            wave_merge_max13_f32<KTOP>(lf, &wiof[(wid - 1) * KTOP], lane);
        }
        __syncthreads();
    }

    // ---- cross-merge the 7 iou lists -> s_iou13 (descending, multiset) ----
    if (wid == 0) {
        int p = 0;
        for (int r = 0; r < KTOP; ++r) {
            float cur = (lane < NW - 1 && p < KTOP) ? wiof[lane * KTOP + p] : NEGINF;
            float bm = wave_max_bc_f32(cur);
            u64 m = __ballot(cur == bm && bm != NEGINF);
            int first = __ffsll(m) - 1;
            if (lane == first) p++;
            if (lane == 0) s_iou13[r] = bm;
        }
    }

    int mode = s_mode;
    if (mode == 1) {   // re-collect at the sound radius Dmax' (rare, exact full scan)
        const float dmax = s_dmax;
        if (tid == 0) s_nc = 0;
        __syncthreads();
        for (int i = tid; i < NPRI; i += SCN_T) {
            float4 p2 = pbp[2 * i + 1];
            if (p2.w > 0.0f) {
                float dx = p2.x - gcx, dy = p2.y - gcy;
                float rad = p2.z * dmax;
                if (dx * dx + dy * dy <= rad * rad * (1.0f + 1e-5f)) {
                    int p = atomicAdd(&s_nc, 1);
                    if (p < CAPC) lcost[p] = i;
                }
            }
        }
        __syncthreads();
        int nc2 = s_nc;
        if (nc2 <= CAPC) {
            if (wid == 0) {
                u64 lf[KTOP];
                #pragma unroll
                for (int s = 0; s < KTOP; ++s) lf[s] = ~0ull;
                for (int k = lane; k < nc2; k += 64) {
                    int i = lcost[k];
                    float4 pb = pbp[2 * i];
                    float4 p2 = pbp[2 * i + 1];
                    float areap = (pb.z - pb.x) * (pb.w - pb.y);
                    float iou = iou_exact(pb, areap, gx1, gy1, gx2, gy2, areag);
                    float ec = cost_exact(p2, gcx, gcy, scores[(size_t)i * NCLS + lab], iou);
                    u64 ck = (((u64)__float_as_uint(ec)) << 32) | (unsigned)i;
                    if (ck < lf[KTOP - 1]) {
                        lf[KTOP - 1] = ck;
                        #pragma unroll
                        for (int s = KTOP - 1; s > 0; --s)
                            if (lf[s] < lf[s - 1]) { u64 t = lf[s]; lf[s] = lf[s - 1]; lf[s - 1] = t; }
                    }
                }
                wave_merge_minN<KTOP>(lf, csel, lane);
            }
        } else {
            mode = 2;   // uniform (s_nc shared)
        }
        __syncthreads();
    }
    if (mode == 2) {   // exact full scan (correctness net)
        u64 lf[KTOP];
        #pragma unroll
        for (int s = 0; s < KTOP; ++s) lf[s] = ~0ull;
        for (int i = tid; i < NPRI; i += SCN_T) {
            float4 pb = pbp[2 * i];
            float4 p2 = pbp[2 * i + 1];
            float areap = (pb.z - pb.x) * (pb.w - pb.y);
            float iou = iou_exact(pb, areap, gx1, gy1, gx2, gy2, areag);
            float ec = INF_F;
            if (p2.w > 0.0f) ec = cost_exact(p2, gcx, gcy, scores[(size_t)i * NCLS + lab], iou);
            u64 k2 = (((u64)__float_as_uint(ec)) << 32) | (unsigned)i;
            if (k2 < lf[KTOP - 1]) {
                lf[KTOP - 1] = k2;
                #pragma unroll
                for (int s = KTOP - 1; s > 0; --s)
                    if (lf[s] < lf[s - 1]) { u64 t = lf[s]; lf[s] = lf[s - 1]; lf[s - 1] = t; }
            }
        }
        wave_merge_minN<KTOP>(lf, &wco[wid * KTOP], lane);
        __syncthreads();
        if (wid == 0) {
            int p = 0;
            for (int r = 0; r < KTOP; ++r) {
                u64 cur = (lane < NW && p < KTOP) ? wco[lane * KTOP + p] : ~0ull;
                u64 bm = wave_min_bc_u64(cur);
                if (cur == bm && bm != ~0ull) p++;
                if (lane == 0) csel[r] = bm;
            }
        }
        __syncthreads();
    }

    // ---- finalize: ks from descending iou sum; scatter selections ----
    __syncthreads();
    if (wid == 0) {
        float tsum = 0.0f;
        #pragma unroll
        for (int r = 0; r < KTOP; ++r) {
            float v = s_iou13[r];
            tsum += (v == NEGINF) ? 0.0f : v;   // descending-order sum (missing = 0, as ref)
        }
        int ks = (int)tsum;
        if (ks < 1) ks = 1;
        if (lane < KTOP && lane < ks) {
            u64 mine = csel[lane];
            if (mine != ~0ull) {
                int idx = (int)(unsigned)(mine & 0xFFFFFFFFull);
                atomicAdd(&count[idx], 1);
                atomicMin(&firstgt[idx], j);
            }
        }
    }
}

// ---------- per-prior finalize; multi-matched priors resolved in-block ----------
__global__ __launch_bounds__(256) void k_assign(
        const float* __restrict__ scores,
        const float4* __restrict__ pbp, const float* __restrict__ gt,
        const void* labels, const int* flag,
        const int* __restrict__ count, const int* __restrict__ firstgt,
        float* __restrict__ out) {
    __shared__ float4 gbox[NGT];
    __shared__ int glab[NGT];
    __shared__ float gcxs[NGT], gcys[NGT], gareas[NGT];
    __shared__ int s_nm;
    __shared__ int s_mlist[256];
    __shared__ u64 red4[4];
    const int tid = threadIdx.x;
    const int is64 = *flag;
    {
        float4 b = ((const float4*)gt)[tid];
        gbox[tid] = b;
        glab[tid] = get_label(labels, tid, is64);
        gcxs[tid] = (b.x + b.z) * 0.5f;
        gcys[tid] = (b.y + b.w) * 0.5f;
        gareas[tid] = (b.z - b.x) * (b.w - b.y);
    }
    if (tid == 0) s_nm = 0;
    __syncthreads();
    const int i = blockIdx.x * 256 + tid;
    const bool act = (i < NPRI);
    if (act) {
        float4 p2 = pbp[2 * i + 1];
        int v = (p2.w > 0.0f) ? 1 : 0;
        int c = count[i];
        float o0 = 0.0f, o1 = -INF_F, o2 = -1.0f;
        if (v && c == 1) {
            int j = firstgt[i];
            float4 pb = pbp[2 * i];
            float areap = (pb.z - pb.x) * (pb.w - pb.y);
            float4 g = gbox[j];
            float iw = fmaxf(fminf(pb.z, g.z) - fmaxf(pb.x, g.x), 0.0f);
            float ih = fmaxf(fminf(pb.w, g.w) - fmaxf(pb.y, g.y), 0.0f);
            float inter = iw * ih;
            float iou = inter / fmaxf(areap + gareas[j] - inter, 1e-6f);
            o0 = (float)(j + 1); o1 = iou; o2 = (float)glab[j];
        } else if (v && c > 1) {
            int p = atomicAdd(&s_nm, 1);
            s_mlist[p] = i;
        }
        out[i] = o0;
        out[NPRI + i] = o1;
        out[2 * NPRI + i] = o2;
    }
    __syncthreads();
    // ---- in-block multi resolution: one GT per thread, block argmin per prior ----
    const int nm = s_nm;
    const int j = tid;
    for (int m = 0; m < nm; ++m) {
        const int ii = s_mlist[m];
        float4 pb = pbp[2 * ii];
        float4 p2 = pbp[2 * ii + 1];
        float areap = (pb.z - pb.x) * (pb.w - pb.y);

        float4 g = gbox[j];
        float iw = fmaxf(fminf(pb.z, g.z) - fmaxf(pb.x, g.x), 0.0f);
        float ih = fmaxf(fminf(pb.w, g.w) - fmaxf(pb.y, g.y), 0.0f);
        float inter = iw * ih;
        float iou = inter / fmaxf(areap + gareas[j] - inter, 1e-6f);
        float dx = p2.x - gcxs[j], dy = p2.y - gcys[j];
        float dist = sqrtf(dx * dx + dy * dy) / p2.z;
        float soft = exp2f((dist - 3.0f) * L10);
        float l = scores[(size_t)ii * NCLS + glab[j]];
        float sig = 1.0f / (1.0f + expf(-l));
        float dd = iou - sig;
        float bce = fmaxf(l, 0.0f) - l * iou + log1pf(expf(-fabsf(l)));
        float cost = bce * (dd * dd) + (-logf(iou + EPS_F) * 3.0f) + soft;

        u64 key = (((u64)__float_as_uint(cost)) << 32) | (unsigned)j;
        u64 v = key;
        #pragma unroll
        for (int off = 32; off > 0; off >>= 1) {
            u64 o = __shfl_down(v, off, 64);
            v = (o < v) ? o : v;
        }
        if ((tid & 63) == 0) red4[tid >> 6] = v;
        __syncthreads();
        u64 best = red4[0];
        #pragma unroll
        for (int q = 1; q < 4; ++q) best = (red4[q] < best) ? red4[q] : best;
        if (key == best) {
            out[ii] = (float)(j + 1);
            out[NPRI + ii] = iou;
            out[2 * NPRI + ii] = (float)glab[j];
        }
        __syncthreads();
    }
}

extern "C" void kernel_launch(void* const* d_in, const int* in_sizes, int n_in,
                              void* d_out, int out_size, void* d_ws, size_t ws_size,
                              hipStream_t stream) {
    const float* scores = (const float*)d_in[0];
    const float* priors = (const float*)d_in[1];
    const float* pboxes = (const float*)d_in[2];
    const float* gt     = (const float*)d_in[3];
    const void*  labels = d_in[4];
    float* out = (float*)d_out;

    char* ws = (char*)d_ws;
    size_t off = 0;
    auto alloc = [&](size_t bytes) { size_t o = off; off = (off + bytes + 255) & ~(size_t)255; return o; };
    int*    flag    = (int*)(ws + alloc(4));
    int*    count   = (int*)(ws + alloc((size_t)NPRI * 4));
    int*    firstgt = (int*)(ws + alloc((size_t)NPRI * 4));
    int*    valid   = (int*)(ws + alloc((size_t)NPRI * 4));
    int*    histI   = (int*)(ws + alloc((size_t)(2 * NB + 2) * 4));   // histI|histC|maxbuf contiguous
    int*    histC   = histI + NB;
    int*    maxbuf  = histI + 2 * NB;
    int*    startI  = (int*)(ws + alloc((size_t)(NB + 1) * 4));
    int*    startC  = (int*)(ws + alloc((size_t)(NB + 1) * 4));
    int*    curI    = (int*)(ws + alloc((size_t)NB * 4));
    int*    curC    = (int*)(ws + alloc((size_t)NB * 4));
    float4* pbp     = (float4*)(ws + alloc((size_t)NPRI * 32));
    float4* A_pb    = (float4*)(ws + alloc((size_t)NPRI * 16));
    float4* A_pc    = (float4*)(ws + alloc((size_t)NPRI * 16));
    (void)ws_size;

    hipMemsetAsync(histI, 0, (size_t)(2 * NB + 2) * 4, stream);   // hists + max slots
    hipLaunchKernelGGL(k_valid, dim3(VAL_BLKS), dim3(256), 0, stream,
                       priors, gt, valid);
    hipLaunchKernelGGL(k_prep, dim3(PREP_BLKS), dim3(256), 0, stream,
                       priors, labels, pboxes, valid, pbp, count, firstgt, flag,
                       histI, histC, maxbuf);
    hipLaunchKernelGGL(k_bins, dim3(1), dim3(NB), 0, stream,
                       histI, histC, startI, startC, curI, curC);
    hipLaunchKernelGGL(k_scatter, dim3(PREP_BLKS), dim3(256), 0, stream,
                       pbp, curI, curC, A_pb, A_pc);
    hipLaunchKernelGGL(k_scan, dim3(NGT), dim3(SCN_T), 0, stream,
                       scores, pbp, A_pb, A_pc, startI, startC, maxbuf,
                       gt, labels, flag, count, firstgt);
    hipLaunchKernelGGL(k_assign, dim3((NPRI + 255) / 256), dim3(256), 0, stream,
                       scores, pbp, gt, labels, flag, count, firstgt, out);
}